// Round 1
// baseline (15061.949 us; speedup 1.0000x reference)
//
#include <hip/hip_runtime.h>

// BiLSTM: B=2048, T=200, D=U=128, 2 layers, bidirectional, merge='ave'.
// Strategy: persistent per-(batch-tile, direction) blocks; fuse both layers
// per timestep; state in LDS/regs; weights streamed from L2 (fit in 4MB/XCD).

#define NB   2048
#define NTT  200
#define ND   128
#define NG   512   // 4*UNITS
#define MT   16    // batch rows per block
#define NTHR 512   // 8 waves
#define AS   132   // LDS stride for A-tiles (x/h), padded
#define ZS   516   // LDS stride for z buffer, padded

__device__ __forceinline__ float rcp_f(float x){ return __builtin_amdgcn_rcpf(x); }
__device__ __forceinline__ float sigm(float x){ return rcp_f(1.f + __expf(-x)); }
// tanh(x) = 1 - 2/(e^{2x}+1): graceful at +/-inf (no NaN)
__device__ __forceinline__ float tanh_f(float x){ return 1.f - 2.f*rcp_f(__expf(2.f*x) + 1.f); }

__device__ __forceinline__ void set4(float (&a)[4], const float4 v){ a[0]=v.x; a[1]=v.y; a[2]=v.z; a[3]=v.w; }
__device__ __forceinline__ void fma4(float (&a)[4], float s, const float4 b){
  a[0] = __builtin_fmaf(s, b.x, a[0]);
  a[1] = __builtin_fmaf(s, b.y, a[1]);
  a[2] = __builtin_fmaf(s, b.z, a[2]);
  a[3] = __builtin_fmaf(s, b.w, a[3]);
}

// acc[2 rows][2 col-chunks][4]: rows r0,r0+1; cols c0..c0+3 and c0+256..c0+259
__device__ __forceinline__ void gemm_acc(float (&acc)[2][2][4],
    const float* A0, const float* A1, const float* __restrict__ Bm, int c0)
{
  #pragma unroll 2
  for (int k4 = 0; k4 < ND; k4 += 4){
    float4 a0 = *(const float4*)(A0 + k4);
    float4 a1 = *(const float4*)(A1 + k4);
    const float* br = Bm + (size_t)k4 * NG + c0;
    #pragma unroll
    for (int kk = 0; kk < 4; ++kk){
      float4 bA = *(const float4*)(br + kk*NG);
      float4 bB = *(const float4*)(br + kk*NG + 256);
      float s0 = (&a0.x)[kk];
      float s1 = (&a1.x)[kk];
      fma4(acc[0][0], s0, bA); fma4(acc[0][1], s0, bB);
      fma4(acc[1][0], s1, bA); fma4(acc[1][1], s1, bB);
    }
  }
}

__device__ __forceinline__ void cell_update(const float* zrow, float (&c)[4], float (&h)[4])
{
  float4 zi4 = *(const float4*)(zrow);
  float4 zf4 = *(const float4*)(zrow + ND);
  float4 zg4 = *(const float4*)(zrow + 2*ND);
  float4 zo4 = *(const float4*)(zrow + 3*ND);
  const float* zi = &zi4.x; const float* zf = &zf4.x;
  const float* zg = &zg4.x; const float* zo = &zo4.x;
  #pragma unroll
  for (int q = 0; q < 4; ++q){
    float iv = sigm(zi[q]);
    float fv = sigm(zf[q]);
    float gv = tanh_f(zg[q]);
    float ov = sigm(zo[q]);
    float cv = __builtin_fmaf(fv, c[q], iv*gv);
    c[q] = cv;
    h[q] = ov * tanh_f(cv);
  }
}

__global__ void __launch_bounds__(NTHR)
bilstm_fused(const float* __restrict__ x,
             const float* __restrict__ Wf, const float* __restrict__ Uf, const float* __restrict__ bf,
             const float* __restrict__ Wb, const float* __restrict__ Ub, const float* __restrict__ bb,
             float* __restrict__ dstFw, float* __restrict__ dstBw, int atomicOut)
{
  __shared__ float xa [MT*AS];   // layer-0 input tile, [r][k]
  __shared__ float h0a[MT*AS];   // layer-0 h state,    [r][k]
  __shared__ float h1a[MT*AS];   // layer-1 h state,    [r][k]
  __shared__ float zb [MT*ZS];   // gate pre-activations, [r][512]

  const int tid = threadIdx.x;
  const int dir = blockIdx.y;          // 0 = fw, 1 = bw
  const int b0  = blockIdx.x * MT;

  const float* W0 = dir ? Wb : Wf;
  const float* U0 = dir ? Ub : Uf;
  const float* B0 = dir ? bb : bf;
  const float* W1 = W0 + ND*NG;
  const float* U1 = U0 + ND*NG;
  const float* B1 = B0 + NG;
  float* dst = dir ? dstBw : dstFw;

  const int lane = tid & 63;
  const int rowg = tid >> 6;           // 0..7
  const int r0   = rowg * 2;           // 2 rows per lane
  const int c0   = lane * 4;           // cols c0..c0+3 and c0+256..c0+259

  const float4 bv00 = *(const float4*)(B0 + c0);
  const float4 bv01 = *(const float4*)(B0 + 256 + c0);
  const float4 bv10 = *(const float4*)(B1 + c0);
  const float4 bv11 = *(const float4*)(B1 + 256 + c0);

  // elementwise mapping: thread owns (er, ej..ej+3), fixed across steps
  const int er = tid >> 5;             // 0..15
  const int ej = (tid & 31) * 4;       // 0..124

  float c0r[4] = {0.f,0.f,0.f,0.f};
  float c1r[4] = {0.f,0.f,0.f,0.f};

  for (int i = tid; i < MT*AS; i += NTHR){ h0a[i] = 0.f; h1a[i] = 0.f; }
  __syncthreads();

  for (int t = 0; t < NTT; ++t){
    const int te = dir ? (NTT-1-t) : t;

    // stage x tile (one float4 per thread, coalesced per row)
    *(float4*)(xa + er*AS + ej) =
        *(const float4*)(x + ((size_t)(b0+er)*NTT + te)*ND + ej);
    __syncthreads();                       // xa ready

    float acc[2][2][4];

    // ---------- layer 0 cell: z = b0 + x_t@W0 + h0@U0
    set4(acc[0][0], bv00); set4(acc[0][1], bv01);
    set4(acc[1][0], bv00); set4(acc[1][1], bv01);
    gemm_acc(acc, xa  + r0*AS, xa  + (r0+1)*AS, W0, c0);
    gemm_acc(acc, h0a + r0*AS, h0a + (r0+1)*AS, U0, c0);
    *(float4*)(zb + (size_t)r0*ZS + c0)           = make_float4(acc[0][0][0],acc[0][0][1],acc[0][0][2],acc[0][0][3]);
    *(float4*)(zb + (size_t)r0*ZS + c0 + 256)     = make_float4(acc[0][1][0],acc[0][1][1],acc[0][1][2],acc[0][1][3]);
    *(float4*)(zb + (size_t)(r0+1)*ZS + c0)       = make_float4(acc[1][0][0],acc[1][0][1],acc[1][0][2],acc[1][0][3]);
    *(float4*)(zb + (size_t)(r0+1)*ZS + c0 + 256) = make_float4(acc[1][1][0],acc[1][1][1],acc[1][1][2],acc[1][1][3]);
    __syncthreads();                       // zb ready; xa free

    {
      float h[4];
      cell_update(zb + (size_t)er*ZS + ej, c0r, h);
      *(float4*)(h0a + er*AS + ej) = make_float4(h[0],h[1],h[2],h[3]);
    }
    __syncthreads();                       // h0a ready

    // ---------- layer 1 cell: z = b1 + h0@W1 + h1@U1
    set4(acc[0][0], bv10); set4(acc[0][1], bv11);
    set4(acc[1][0], bv10); set4(acc[1][1], bv11);
    gemm_acc(acc, h0a + r0*AS, h0a + (r0+1)*AS, W1, c0);
    gemm_acc(acc, h1a + r0*AS, h1a + (r0+1)*AS, U1, c0);
    *(float4*)(zb + (size_t)r0*ZS + c0)           = make_float4(acc[0][0][0],acc[0][0][1],acc[0][0][2],acc[0][0][3]);
    *(float4*)(zb + (size_t)r0*ZS + c0 + 256)     = make_float4(acc[0][1][0],acc[0][1][1],acc[0][1][2],acc[0][1][3]);
    *(float4*)(zb + (size_t)(r0+1)*ZS + c0)       = make_float4(acc[1][0][0],acc[1][0][1],acc[1][0][2],acc[1][0][3]);
    *(float4*)(zb + (size_t)(r0+1)*ZS + c0 + 256) = make_float4(acc[1][1][0],acc[1][1][1],acc[1][1][2],acc[1][1][3]);
    __syncthreads();                       // zb ready; all h1a reads done

    {
      float h[4];
      cell_update(zb + (size_t)er*ZS + ej, c1r, h);
      *(float4*)(h1a + er*AS + ej) = make_float4(h[0],h[1],h[2],h[3]);
      float* gp = dst + ((size_t)(b0+er)*NTT + te)*ND + ej;
      if (atomicOut){
        atomicAdd(gp+0, 0.5f*h[0]); atomicAdd(gp+1, 0.5f*h[1]);
        atomicAdd(gp+2, 0.5f*h[2]); atomicAdd(gp+3, 0.5f*h[3]);
      } else {
        *(float4*)gp = make_float4(0.5f*h[0],0.5f*h[1],0.5f*h[2],0.5f*h[3]);
      }
    }
    // no trailing barrier needed: next-iter barriers order h1a/zb reuse
  }
}

__global__ void __launch_bounds__(256)
merge_add(float* __restrict__ out, const float* __restrict__ ws, int n4)
{
  int i = blockIdx.x*blockDim.x + threadIdx.x;
  const int stride = gridDim.x*blockDim.x;
  for (; i < n4; i += stride){
    float4 a = ((const float4*)out)[i];
    float4 b = ((const float4*)ws)[i];
    a.x += b.x; a.y += b.y; a.z += b.z; a.w += b.w;
    ((float4*)out)[i] = a;
  }
}

extern "C" void kernel_launch(void* const* d_in, const int* in_sizes, int n_in,
                              void* d_out, int out_size, void* d_ws, size_t ws_size,
                              hipStream_t stream)
{
  const float* x  = (const float*)d_in[0];
  const float* Wf = (const float*)d_in[1];
  const float* Uf = (const float*)d_in[2];
  const float* bf = (const float*)d_in[3];
  const float* Wb = (const float*)d_in[4];
  const float* Ub = (const float*)d_in[5];
  const float* bb = (const float*)d_in[6];
  float* out = (float*)d_out;

  const size_t need = (size_t)out_size * sizeof(float);
  dim3 grid(NB/MT, 2), blk(NTHR);

  if (ws_size >= need){
    // fw writes 0.5*h1f to out, bw writes 0.5*h1b to ws, then merge-add.
    float* ws = (float*)d_ws;
    bilstm_fused<<<grid, blk, 0, stream>>>(x,Wf,Uf,bf,Wb,Ub,bb,out,ws,0);
    merge_add<<<2048, 256, 0, stream>>>(out, ws, out_size/4);
  } else {
    // fallback: zero out, both directions atomically accumulate 0.5*h.
    // (0+a)+b == (0+b)+a bitwise for IEEE fp32 adds -> deterministic.
    hipMemsetAsync(out, 0, need, stream);
    bilstm_fused<<<grid, blk, 0, stream>>>(x,Wf,Uf,bf,Wb,Ub,bb,out,out,1);
  }
}